// Round 8
// baseline (9001.614 us; speedup 1.0000x reference)
//
#include <hip/hip_runtime.h>
#include <hip/hip_bf16.h>

#define DIM 1024
#define HID 4096
#define NH 16
#define HD 64
#define BB 4
#define SS 2048
#define NROW (BB*SS)   // 8192

// ---------------- LayerNorm fp32 -> fp32: one row (1024) per 256-thread block ----------------
__global__ __launch_bounds__(256) void ln32(const float* __restrict__ x,
                                            const float* __restrict__ g,
                                            const float* __restrict__ bta,
                                            float* __restrict__ out) {
  int row = blockIdx.x;
  int t = threadIdx.x;
  int lane = t & 63, wid = t >> 6;
  float4 v = *(const float4*)(x + (size_t)row*DIM + t*4);
  float f[4] = {v.x, v.y, v.z, v.w};
  float s1 = 0.f, s2 = 0.f;
#pragma unroll
  for (int j = 0; j < 4; j++) { s1 += f[j]; s2 += f[j]*f[j]; }
#pragma unroll
  for (int off = 32; off > 0; off >>= 1) { s1 += __shfl_xor(s1, off); s2 += __shfl_xor(s2, off); }
  __shared__ float red[8];
  if (lane == 0) { red[wid] = s1; red[4+wid] = s2; }
  __syncthreads();
  s1 = red[0]+red[1]+red[2]+red[3];
  s2 = red[4]+red[5]+red[6]+red[7];
  float mu = s1 * (1.0f/DIM);
  float var = s2 * (1.0f/DIM) - mu*mu;
  float rs = rsqrtf(var + 1e-5f);
  float4 gv = *(const float4*)(g + t*4);
  float4 bv = *(const float4*)(bta + t*4);
  float4 o;
  o.x = (f[0]-mu)*rs*gv.x + bv.x;
  o.y = (f[1]-mu)*rs*gv.y + bv.y;
  o.z = (f[2]-mu)*rs*gv.z + bv.z;
  o.w = (f[3]-mu)*rs*gv.w + bv.w;
  *(float4*)(out + (size_t)row*DIM + t*4) = o;
}

// ---------------- fp32 LDS-tiled GEMM: C[M,N] = A[M,K] @ W[K,N] ----------------
// EPI: 0 = none, 1 = relu, 3 = add fp32 residual. 64x64 tile, BK=16, 256 threads, 4x4/thread.
template<int EPI>
__global__ __launch_bounds__(256) void gemm32(const float* __restrict__ A, int lda,
                                              const float* __restrict__ W, int ldw,
                                              float* __restrict__ C, int ldc,
                                              const float* __restrict__ Res, int ldr,
                                              int K) {
  __shared__ float As[64][17];
  __shared__ float Bs[16][65];
  int t = threadIdx.x;
  int bm = blockIdx.y*64, bn = blockIdx.x*64;
  int ty = t >> 4, tx = t & 15;
  float acc[4][4] = {};
  for (int k0 = 0; k0 < K; k0 += 16) {
    int ra = t >> 2, ca = (t & 3)*4;           // A tile: 64 rows x 16 cols
#pragma unroll
    for (int i = 0; i < 4; ++i)
      As[ra][ca+i] = A[(size_t)(bm + ra)*lda + k0 + ca + i];
    int rb = t >> 6, cb = (t & 63);            // W tile: 16 rows x 64 cols (4 row-chunks)
#pragma unroll
    for (int i = 0; i < 4; ++i)
      Bs[rb*4 + i][cb] = W[(size_t)(k0 + rb*4 + i)*ldw + bn + cb];
    __syncthreads();
#pragma unroll
    for (int kk = 0; kk < 16; ++kk)
#pragma unroll
      for (int i = 0; i < 4; ++i)
#pragma unroll
        for (int j = 0; j < 4; ++j)
          acc[i][j] += As[ty*4+i][kk] * Bs[kk][tx*4+j];
    __syncthreads();
  }
#pragma unroll
  for (int i = 0; i < 4; ++i) {
    int r = bm + ty*4 + i;
#pragma unroll
    for (int j = 0; j < 4; ++j) {
      int c = bn + tx*4 + j;
      float v = acc[i][j];
      if constexpr (EPI == 1) v = fmaxf(v, 0.f);
      if constexpr (EPI == 3) v += Res[(size_t)r*ldr + c];
      C[(size_t)r*ldc + c] = v;
    }
  }
}

// ---------------- scalar causal flash attention, pure fp32 ----------------
// One thread per q-row; all lanes of a block walk the same k together (broadcast loads).
__global__ __launch_bounds__(64) void attn32(const float* __restrict__ qkv,
                                             float* __restrict__ ao) {
  int lane = threadIdx.x;
  int q = blockIdx.x*64 + lane;
  int z = blockIdx.y; int b = z >> 4, h = z & 15;
  const int ld = 3*DIM;
  const float* qp = qkv + (size_t)(b*SS + q)*ld + h*HD;
  float Q[64];
#pragma unroll
  for (int c = 0; c < 16; ++c) {
    float4 v = *(const float4*)(qp + c*4);
    Q[c*4+0] = v.x; Q[c*4+1] = v.y; Q[c*4+2] = v.z; Q[c*4+3] = v.w;
  }
  float m = -1e30f, l = 0.f;
  float acc[64];
#pragma unroll
  for (int d = 0; d < 64; ++d) acc[d] = 0.f;
  for (int k = 0; k <= q; ++k) {
    const float* kp = qkv + (size_t)(b*SS + k)*ld + DIM + h*HD;
    float s = 0.f;
#pragma unroll
    for (int c = 0; c < 16; ++c) {
      float4 v = *(const float4*)(kp + c*4);
      s += Q[c*4+0]*v.x + Q[c*4+1]*v.y + Q[c*4+2]*v.z + Q[c*4+3]*v.w;
    }
    s *= 0.125f;                        // 1/sqrt(HD) = 1/8  <-- single change this round
    float mn = fmaxf(m, s);
    float sc = __expf(m - mn);
    float p = __expf(s - mn);
    l = l*sc + p;
    const float* vp = qkv + (size_t)(b*SS + k)*ld + 2*DIM + h*HD;
#pragma unroll
    for (int c = 0; c < 16; ++c) {
      float4 v = *(const float4*)(vp + c*4);
      acc[c*4+0] = acc[c*4+0]*sc + p*v.x;
      acc[c*4+1] = acc[c*4+1]*sc + p*v.y;
      acc[c*4+2] = acc[c*4+2]*sc + p*v.z;
      acc[c*4+3] = acc[c*4+3]*sc + p*v.w;
    }
    m = mn;
  }
  float rl = 1.0f / l;
  float* op = ao + (size_t)(b*SS + q)*DIM + h*HD;
#pragma unroll
  for (int d = 0; d < 64; ++d) op[d] = acc[d]*rl;
}

extern "C" void kernel_launch(void* const* d_in, const int* in_sizes, int n_in,
                              void* d_out, int out_size, void* d_ws, size_t ws_size,
                              hipStream_t stream) {
  (void)in_sizes; (void)n_in; (void)out_size; (void)ws_size;
  const float* x    = (const float*)d_in[0];
  // d_in[1] = mask: causal with -1e9 fill -> applied analytically, ignored
  const float* wq   = (const float*)d_in[2];
  const float* wk   = (const float*)d_in[3];
  const float* wv   = (const float*)d_in[4];
  const float* wo   = (const float*)d_in[5];
  const float* w1   = (const float*)d_in[6];
  const float* w2   = (const float*)d_in[7];
  const float* ln1w = (const float*)d_in[8];
  const float* ln1b = (const float*)d_in[9];
  const float* ln2w = (const float*)d_in[10];
  const float* ln2b = (const float*)d_in[11];
  float* out = (float*)d_out;   // fp32 output

  float* fws = (float*)d_ws;
  float* f_xn  = fws;                          // [NROW][DIM]: LN1 out -> attn out -> LN2 out
  float* f_qkv = fws + (size_t)NROW*DIM;       // [NROW][3*DIM]
  float* f_ff1 = f_qkv;                        // [NROW][HID] overlaps qkv (dead after attention)

  dim3 B256(256);
  // xn = LN1(x)
  ln32<<<NROW, B256, 0, stream>>>(x, ln1w, ln1b, f_xn);
  // q|k|v = xn @ wq|wk|wv
  gemm32<0><<<dim3(DIM/64, NROW/64), B256, 0, stream>>>(f_xn, DIM, wq, DIM, f_qkv,         3*DIM, nullptr, 0, DIM);
  gemm32<0><<<dim3(DIM/64, NROW/64), B256, 0, stream>>>(f_xn, DIM, wk, DIM, f_qkv + DIM,   3*DIM, nullptr, 0, DIM);
  gemm32<0><<<dim3(DIM/64, NROW/64), B256, 0, stream>>>(f_xn, DIM, wv, DIM, f_qkv + 2*DIM, 3*DIM, nullptr, 0, DIM);
  // attention (writes into f_xn — LN1 out is dead now)
  attn32<<<dim3(SS/64, BB*NH), dim3(64), 0, stream>>>(f_qkv, f_xn);
  // h = x + attn @ wo  (fp32 h in d_out)
  gemm32<3><<<dim3(DIM/64, NROW/64), B256, 0, stream>>>(f_xn, DIM, wo, DIM, out, DIM, x, DIM, DIM);
  // hn = LN2(h)
  ln32<<<NROW, B256, 0, stream>>>(out, ln2w, ln2b, f_xn);
  // ff1 = relu(hn @ w1)   (overlaps dead qkv)
  gemm32<1><<<dim3(HID/64, NROW/64), B256, 0, stream>>>(f_xn, DIM, w1, HID, f_ff1, HID, nullptr, 0, DIM);
  // out = h + ff1 @ w2   (in-place fp32 residual, per-element read+write)
  gemm32<3><<<dim3(DIM/64, NROW/64), B256, 0, stream>>>(f_ff1, HID, w2, DIM, out, DIM, out, DIM, HID);
}

// Round 9
// 655.986 us; speedup vs baseline: 13.7223x; 13.7223x over previous
//
#include <hip/hip_runtime.h>
#include <hip/hip_bf16.h>
#include <type_traits>

#define DIM 1024
#define HID 4096
#define NH 16
#define HD 64
#define BB 4
#define SS 2048
#define NROW (BB*SS)   // 8192

typedef __attribute__((ext_vector_type(8))) short short8;
typedef __attribute__((ext_vector_type(4))) short short4v;
typedef __attribute__((ext_vector_type(4))) float f32x4;

__device__ __forceinline__ void gload16(const void* src, void* lds) {
  __builtin_amdgcn_global_load_lds(
      (const __attribute__((address_space(1))) unsigned int*)src,
      (__attribute__((address_space(3))) unsigned int*)lds, 16, 0, 0);
}
__device__ __forceinline__ short f2b(float f) {
  return __builtin_bit_cast(short, __float2bfloat16(f));
}
__device__ __forceinline__ float b2f(short s) {
  return __uint_as_float(((unsigned)(unsigned short)s) << 16);
}

// ---------------- LayerNorm: one row (1024) per 256-thread block ----------------
// fp32 in, bf16 out.
__global__ __launch_bounds__(256) void ln_k(const float* __restrict__ x,
                                            const float* __restrict__ g,
                                            const float* __restrict__ bta,
                                            short* __restrict__ out) {
  int row = blockIdx.x;
  int t = threadIdx.x;
  int lane = t & 63, wid = t >> 6;
  float4 v = *(const float4*)(x + (size_t)row*DIM + t*4);
  float f[4] = {v.x, v.y, v.z, v.w};
  float s1 = 0.f, s2 = 0.f;
#pragma unroll
  for (int j = 0; j < 4; j++) { s1 += f[j]; s2 += f[j]*f[j]; }
#pragma unroll
  for (int off = 32; off > 0; off >>= 1) { s1 += __shfl_xor(s1, off); s2 += __shfl_xor(s2, off); }
  __shared__ float red[8];
  if (lane == 0) { red[wid] = s1; red[4+wid] = s2; }
  __syncthreads();
  s1 = red[0]+red[1]+red[2]+red[3];
  s2 = red[4]+red[5]+red[6]+red[7];
  float mu = s1 * (1.0f/DIM);
  float var = s2 * (1.0f/DIM) - mu*mu;
  float rs = rsqrtf(var + 1e-5f);
  float4 gv = *(const float4*)(g + t*4);
  float4 bv = *(const float4*)(bta + t*4);
  short4v o;
  o[0] = f2b((f[0]-mu)*rs*gv.x + bv.x);
  o[1] = f2b((f[1]-mu)*rs*gv.y + bv.y);
  o[2] = f2b((f[2]-mu)*rs*gv.z + bv.z);
  o[3] = f2b((f[3]-mu)*rs*gv.w + bv.w);
  *(short4v*)(out + (size_t)row*DIM + t*4) = o;
}

// ------------- fp32 -> bf16 2D transpose (R,C multiples of 64) -------------
__global__ __launch_bounds__(256) void transp_f2b(const float* __restrict__ in, short* __restrict__ out,
                                                  int R, int C) {
  __shared__ __align__(16) short tile[64][72];
  int r0 = blockIdx.x*64, c0 = blockIdx.y*64;
  int t = threadIdx.x;
  int cr = t >> 4;           // 0..15
  int cc4 = (t & 15) * 4;    // 0..60
#pragma unroll
  for (int i = 0; i < 4; i++) {
    float4 v = *(const float4*)(in + (size_t)(r0 + cr + i*16)*C + c0 + cc4);
    tile[cr + i*16][cc4 + 0] = f2b(v.x);
    tile[cr + i*16][cc4 + 1] = f2b(v.y);
    tile[cr + i*16][cc4 + 2] = f2b(v.z);
    tile[cr + i*16][cc4 + 3] = f2b(v.w);
  }
  __syncthreads();
  int rr = t >> 3, cc = (t & 7) * 8;
#pragma unroll
  for (int i = 0; i < 2; i++) {
    int oc = rr + i*32;
    short8 v;
#pragma unroll
    for (int j = 0; j < 8; j++) v[j] = tile[cc + j][oc];
    *(short8*)(out + (size_t)(c0 + oc)*R + r0 + cc) = v;
  }
}

// ---------------- V transpose: qkv v-cols [b,s,h,d] -> vt [b,h,d,s] ----------------
__global__ __launch_bounds__(256) void vtrans(const short* __restrict__ qkv, short* __restrict__ vt) {
  __shared__ __align__(16) short tile[64][72];
  int s0 = blockIdx.x*64;
  int z = blockIdx.y; int b = z >> 4, h = z & 15;
  int t = threadIdx.x;
  int rr = t >> 3, cc = (t & 7) * 8;
#pragma unroll
  for (int i = 0; i < 2; i++) {
    short8 v = *(const short8*)(qkv + (size_t)(b*SS + s0 + rr + i*32)*(3*DIM) + 2*DIM + h*HD + cc);
    *(short8*)&tile[rr + i*32][cc] = v;
  }
  __syncthreads();
#pragma unroll
  for (int i = 0; i < 2; i++) {
    int d = rr + i*32;
    short8 v;
#pragma unroll
    for (int j = 0; j < 8; j++) v[j] = tile[cc + j][d];
    *(short8*)(vt + ((size_t)z*HD + d)*SS + s0 + cc) = v;
  }
}

// ---------------- GEMM: C[M,N] = A[M,K] * Bt[N,K]^T  (m97 structure) ----------------
// EPI: 0 = none, 1 = relu, 3 = add fp32 residual.  CT: short (bf16 out) or float (fp32 out).
template<int EPI, typename CT>
__global__ __launch_bounds__(256) void gemm_bt(const short* __restrict__ A, int lda,
                                               const short* __restrict__ Bt, int ldb,
                                               CT* C, int ldc,
                                               const float* Res, int ldr,
                                               int K) {
  __shared__ __align__(16) short ldsA[128*32];
  __shared__ __align__(16) short ldsB[128*32];
  int t = threadIdx.x, lane = t & 63, wid = t >> 6;
  int bm = blockIdx.x*128, bn = blockIdx.y*128;
  int wr = wid >> 1, wc = wid & 1;
  f32x4 z4 = {0.f, 0.f, 0.f, 0.f};
  f32x4 acc[4][4];
#pragma unroll
  for (int m = 0; m < 4; m++)
#pragma unroll
    for (int n = 0; n < 4; n++) acc[m][n] = z4;
  const short* pa = A + (size_t)(bm + (t >> 2))*lda + (t & 3)*8;
  const short* pb = Bt + (size_t)(bn + (t >> 2))*ldb + (t & 3)*8;
  for (int k0 = 0; k0 < K; k0 += 32) {
    gload16(pa,                    &ldsA[wid*512]);
    gload16(pa + (size_t)64*lda,   &ldsA[2048 + wid*512]);
    gload16(pb,                    &ldsB[wid*512]);
    gload16(pb + (size_t)64*ldb,   &ldsB[2048 + wid*512]);
    pa += 32; pb += 32;
    __syncthreads();
    short8 af[4], bfr[4];
#pragma unroll
    for (int m = 0; m < 4; m++)
      af[m] = *(const short8*)&ldsA[(wr*64 + m*16 + (lane & 15))*32 + (lane >> 4)*8];
#pragma unroll
    for (int n = 0; n < 4; n++)
      bfr[n] = *(const short8*)&ldsB[(wc*64 + n*16 + (lane & 15))*32 + (lane >> 4)*8];
#pragma unroll
    for (int m = 0; m < 4; m++)
#pragma unroll
      for (int n = 0; n < 4; n++)
        acc[m][n] = __builtin_amdgcn_mfma_f32_16x16x32_bf16(af[m], bfr[n], acc[m][n], 0, 0, 0);
    __syncthreads();
  }
#pragma unroll
  for (int m = 0; m < 4; m++) {
    int r0 = bm + wr*64 + m*16 + ((lane >> 4) << 2);
#pragma unroll
    for (int n = 0; n < 4; n++) {
      int c = bn + wc*64 + n*16 + (lane & 15);
#pragma unroll
      for (int r = 0; r < 4; r++) {
        float v = acc[m][n][r];
        if constexpr (EPI == 1) v = fmaxf(v, 0.0f);
        if constexpr (EPI == 3) v += Res[(size_t)(r0 + r)*ldr + c];
        if constexpr (std::is_same<CT, float>::value)
          C[(size_t)(r0 + r)*ldc + c] = v;
        else
          C[(size_t)(r0 + r)*ldc + c] = f2b(v);
      }
    }
  }
}

// ---------------- causal flash attention (MFMA) ----------------
// grid: (S/64, B*NH); block 256 = 4 waves; wave w owns q-rows q0+w*16..+15.
// Reads Q,K from qkv; V via pre-transposed vt [b,h,d,s]; writes attn into qkv v-columns.
// Score scale: 1/sqrt(HD) = 0.125 (verified round 8).
__global__ __launch_bounds__(256) void attn_k(short* qkv, const short* __restrict__ vt) {
  __shared__ __align__(16) short ldsK[64*64];
  __shared__ __align__(16) short ldsV[64*64];
  __shared__ __align__(16) short ldsP[4][16*64];
  int t = threadIdx.x, lane = t & 63, wid = t >> 6;
  int q0 = blockIdx.x*64;
  int z = blockIdx.y; int b = z >> 4, h = z & 15;
  const int ld = 3*DIM;
  short8 qf[2];
  {
    const short* qp = qkv + (size_t)(b*SS + q0 + wid*16 + (lane & 15))*ld + h*HD + (lane >> 4)*8;
    qf[0] = *(const short8*)qp;
    qf[1] = *(const short8*)(qp + 32);
  }
  f32x4 z4 = {0.f, 0.f, 0.f, 0.f};
  f32x4 accO[4];
#pragma unroll
  for (int n = 0; n < 4; n++) accO[n] = z4;
  float m_r[4], l_r[4];
#pragma unroll
  for (int r = 0; r < 4; r++) { m_r[r] = -1e30f; l_r[r] = 0.f; }
  int ntiles = blockIdx.x + 1;   // causal: kv tiles 0 .. q-tile
  for (int it = 0; it < ntiles; ++it) {
    int kv0 = it*64;
    {
      const short* sk = qkv + (size_t)(b*SS + kv0 + (t >> 3))*ld + DIM + h*HD + (t & 7)*8;
      gload16(sk,                  &ldsK[wid*512]);
      gload16(sk + (size_t)32*ld,  &ldsK[2048 + wid*512]);
      const short* sv = vt + ((size_t)z*HD + (t >> 3))*SS + kv0 + (t & 7)*8;
      gload16(sv,                  &ldsV[wid*512]);
      gload16(sv + (size_t)32*SS,  &ldsV[2048 + wid*512]);
    }
    __syncthreads();
    f32x4 sacc[4];
#pragma unroll
    for (int n = 0; n < 4; n++) sacc[n] = z4;
#pragma unroll
    for (int n = 0; n < 4; n++) {
#pragma unroll
      for (int kk = 0; kk < 2; kk++) {
        short8 kb = *(const short8*)&ldsK[(n*16 + (lane & 15))*64 + kk*32 + (lane >> 4)*8];
        sacc[n] = __builtin_amdgcn_mfma_f32_16x16x32_bf16(qf[kk], kb, sacc[n], 0, 0, 0);
      }
    }
    float al[4];
#pragma unroll
    for (int r = 0; r < 4; r++) {
      int qg = q0 + wid*16 + ((lane >> 4) << 2) + r;
      float mx = -1e30f;
#pragma unroll
      for (int n = 0; n < 4; n++) {
        int kg = kv0 + n*16 + (lane & 15);
        float s = sacc[n][r] * 0.125f;       // 1/sqrt(HD) = 1/8 (verified r8)
        s = (kg <= qg) ? s : -1e30f;         // causal mask
        sacc[n][r] = s;
        mx = fmaxf(mx, s);
      }
#pragma unroll
      for (int off = 1; off < 16; off <<= 1) mx = fmaxf(mx, __shfl_xor(mx, off));
      float mn = fmaxf(m_r[r], mx);
      al[r] = __expf(m_r[r] - mn);
      float rsum = 0.f;
#pragma unroll
      for (int n = 0; n < 4; n++) {
        float p = __expf(sacc[n][r] - mn);
        sacc[n][r] = p;
        rsum += p;
      }
#pragma unroll
      for (int off = 1; off < 16; off <<= 1) rsum += __shfl_xor(rsum, off);
      l_r[r] = l_r[r]*al[r] + rsum;
      m_r[r] = mn;
    }
#pragma unroll
    for (int n = 0; n < 4; n++)
#pragma unroll
      for (int r = 0; r < 4; r++) accO[n][r] *= al[r];
    // P (D-layout) -> per-wave LDS in A-operand layout
#pragma unroll
    for (int n = 0; n < 4; n++)
#pragma unroll
      for (int r = 0; r < 4; r++)
        ldsP[wid][(((lane >> 4) << 2) + r)*64 + n*16 + (lane & 15)] = f2b(sacc[n][r]);
    __syncthreads();
#pragma unroll
    for (int nn = 0; nn < 4; nn++) {
#pragma unroll
      for (int kk = 0; kk < 2; kk++) {
        short8 pfr = *(const short8*)&ldsP[wid][(lane & 15)*64 + kk*32 + (lane >> 4)*8];
        short8 vb  = *(const short8*)&ldsV[(nn*16 + (lane & 15))*64 + kk*32 + (lane >> 4)*8];
        accO[nn] = __builtin_amdgcn_mfma_f32_16x16x32_bf16(pfr, vb, accO[nn], 0, 0, 0);
      }
    }
    __syncthreads();
  }
#pragma unroll
  for (int nn = 0; nn < 4; nn++) {
#pragma unroll
    for (int r = 0; r < 4; r++) {
      int qg = q0 + wid*16 + ((lane >> 4) << 2) + r;
      float ov = accO[nn][r] / l_r[r];
      qkv[(size_t)(b*SS + qg)*ld + 2*DIM + h*HD + nn*16 + (lane & 15)] = f2b(ov);
    }
  }
}

extern "C" void kernel_launch(void* const* d_in, const int* in_sizes, int n_in,
                              void* d_out, int out_size, void* d_ws, size_t ws_size,
                              hipStream_t stream) {
  (void)in_sizes; (void)n_in; (void)out_size; (void)ws_size;
  const float* x    = (const float*)d_in[0];
  // d_in[1] = mask: causal with -1e9 fill -> applied analytically, ignored
  const float* wq   = (const float*)d_in[2];
  const float* wk   = (const float*)d_in[3];
  const float* wv   = (const float*)d_in[4];
  const float* wo   = (const float*)d_in[5];
  const float* w1   = (const float*)d_in[6];
  const float* w2   = (const float*)d_in[7];
  const float* ln1w = (const float*)d_in[8];
  const float* ln1b = (const float*)d_in[9];
  const float* ln2w = (const float*)d_in[10];
  const float* ln2b = (const float*)d_in[11];
  float* out = (float*)d_out;   // fp32 output (verified r8)

  short* ws = (short*)d_ws;
  size_t o = 0;
  short* wqkvT = ws + o; o += (size_t)3*DIM*DIM;   // [3072][1024] bf16
  short* woT   = ws + o; o += (size_t)DIM*DIM;     // [1024][1024]
  short* w1T   = ws + o; o += (size_t)HID*DIM;     // [4096][1024]
  short* w2T   = ws + o; o += (size_t)DIM*HID;     // [1024][4096]
  short* xn    = ws + o; o += (size_t)NROW*DIM;    // LN1 out -> LN2 out (disjoint lifetimes)
  short* qkv   = ws + o; o += (size_t)NROW*3*DIM;  // q|k|v cols; v cols overwritten by attn out
  short* ff1   = ws + o; o += (size_t)NROW*HID;    // relu(hn@w1); front 16MB doubles as vt earlier
  short* vtb   = ff1;                              // [b,h,d,s] — lifetime disjoint from ff1

  dim3 B256(256);
  // weight transposes (fp32 -> bf16, B^T convention for gemm_bt)
  transp_f2b<<<dim3(16,16), B256, 0, stream>>>(wq, wqkvT,             DIM, DIM);
  transp_f2b<<<dim3(16,16), B256, 0, stream>>>(wk, wqkvT + DIM*DIM,   DIM, DIM);
  transp_f2b<<<dim3(16,16), B256, 0, stream>>>(wv, wqkvT + 2*DIM*DIM, DIM, DIM);
  transp_f2b<<<dim3(16,16), B256, 0, stream>>>(wo, woT, DIM, DIM);
  transp_f2b<<<dim3(16,64), B256, 0, stream>>>(w1, w1T, DIM, HID);
  transp_f2b<<<dim3(64,16), B256, 0, stream>>>(w2, w2T, HID, DIM);
  // xn = LN1(x)   (fp32 in, bf16 out)
  ln_k<<<NROW, B256, 0, stream>>>(x, ln1w, ln1b, xn);
  // qkv = xn @ [wq|wk|wv]   (bf16 out)
  gemm_bt<0, short><<<dim3(NROW/128, 3*DIM/128), B256, 0, stream>>>(xn, DIM, wqkvT, DIM, qkv, 3*DIM, nullptr, 0, DIM);
  // vt = transpose(v) per (b,h)
  vtrans<<<dim3(SS/64, BB*NH), B256, 0, stream>>>(qkv, vtb);
  // attention (writes into qkv v-columns, bf16)
  attn_k<<<dim3(SS/64, BB*NH), B256, 0, stream>>>(qkv, vtb);
  // h = x + attn @ wo   (fp32 h in d_out)
  gemm_bt<3, float><<<dim3(NROW/128, DIM/128), B256, 0, stream>>>(qkv + 2*DIM, 3*DIM, woT, DIM, out, DIM, x, DIM, DIM);
  // hn = LN2(h) (fp32 in, bf16 out into xn)
  ln_k<<<NROW, B256, 0, stream>>>(out, ln2w, ln2b, xn);
  // ff1 = relu(hn @ w1)  (bf16 out)
  gemm_bt<1, short><<<dim3(NROW/128, HID/128), B256, 0, stream>>>(xn, DIM, w1T, DIM, ff1, HID, nullptr, 0, DIM);
  // out = h + ff1 @ w2   (fp32 in-place residual: each element read+written by its own thread)
  gemm_bt<3, float><<<dim3(NROW/128, DIM/128), B256, 0, stream>>>(ff1, HID, w2T, HID, out, DIM, out, DIM, HID);
}

// Round 10
// 589.935 us; speedup vs baseline: 15.2587x; 1.1120x over previous
//
#include <hip/hip_runtime.h>
#include <hip/hip_bf16.h>
#include <type_traits>

#define DIM 1024
#define HID 4096
#define NH 16
#define HD 64
#define BB 4
#define SS 2048
#define NROW (BB*SS)   // 8192

typedef __attribute__((ext_vector_type(8))) short short8;
typedef __attribute__((ext_vector_type(4))) short short4v;
typedef __attribute__((ext_vector_type(4))) float f32x4;

__device__ __forceinline__ void gload16(const void* src, void* lds) {
  __builtin_amdgcn_global_load_lds(
      (const __attribute__((address_space(1))) unsigned int*)src,
      (__attribute__((address_space(3))) unsigned int*)lds, 16, 0, 0);
}
__device__ __forceinline__ short f2b(float f) {
  return __builtin_bit_cast(short, __float2bfloat16(f));
}
__device__ __forceinline__ float b2f(short s) {
  return __uint_as_float(((unsigned)(unsigned short)s) << 16);
}

// ---------------- LayerNorm: one row (1024) per 256-thread block ----------------
// fp32 in, bf16 out.
__global__ __launch_bounds__(256) void ln_k(const float* __restrict__ x,
                                            const float* __restrict__ g,
                                            const float* __restrict__ bta,
                                            short* __restrict__ out) {
  int row = blockIdx.x;
  int t = threadIdx.x;
  int lane = t & 63, wid = t >> 6;
  float4 v = *(const float4*)(x + (size_t)row*DIM + t*4);
  float f[4] = {v.x, v.y, v.z, v.w};
  float s1 = 0.f, s2 = 0.f;
#pragma unroll
  for (int j = 0; j < 4; j++) { s1 += f[j]; s2 += f[j]*f[j]; }
#pragma unroll
  for (int off = 32; off > 0; off >>= 1) { s1 += __shfl_xor(s1, off); s2 += __shfl_xor(s2, off); }
  __shared__ float red[8];
  if (lane == 0) { red[wid] = s1; red[4+wid] = s2; }
  __syncthreads();
  s1 = red[0]+red[1]+red[2]+red[3];
  s2 = red[4]+red[5]+red[6]+red[7];
  float mu = s1 * (1.0f/DIM);
  float var = s2 * (1.0f/DIM) - mu*mu;
  float rs = rsqrtf(var + 1e-5f);
  float4 gv = *(const float4*)(g + t*4);
  float4 bv = *(const float4*)(bta + t*4);
  short4v o;
  o[0] = f2b((f[0]-mu)*rs*gv.x + bv.x);
  o[1] = f2b((f[1]-mu)*rs*gv.y + bv.y);
  o[2] = f2b((f[2]-mu)*rs*gv.z + bv.z);
  o[3] = f2b((f[3]-mu)*rs*gv.w + bv.w);
  *(short4v*)(out + (size_t)row*DIM + t*4) = o;
}

// ------------- fp32 -> bf16 2D transpose (R,C multiples of 64) -------------
__global__ __launch_bounds__(256) void transp_f2b(const float* __restrict__ in, short* __restrict__ out,
                                                  int R, int C) {
  __shared__ __align__(16) short tile[64][72];
  int r0 = blockIdx.x*64, c0 = blockIdx.y*64;
  int t = threadIdx.x;
  int cr = t >> 4;           // 0..15
  int cc4 = (t & 15) * 4;    // 0..60
#pragma unroll
  for (int i = 0; i < 4; i++) {
    float4 v = *(const float4*)(in + (size_t)(r0 + cr + i*16)*C + c0 + cc4);
    tile[cr + i*16][cc4 + 0] = f2b(v.x);
    tile[cr + i*16][cc4 + 1] = f2b(v.y);
    tile[cr + i*16][cc4 + 2] = f2b(v.z);
    tile[cr + i*16][cc4 + 3] = f2b(v.w);
  }
  __syncthreads();
  int rr = t >> 3, cc = (t & 7) * 8;
#pragma unroll
  for (int i = 0; i < 2; i++) {
    int oc = rr + i*32;
    short8 v;
#pragma unroll
    for (int j = 0; j < 8; j++) v[j] = tile[cc + j][oc];
    *(short8*)(out + (size_t)(c0 + oc)*R + r0 + cc) = v;
  }
}

// ---------------- V transpose: qkv v-cols [b,s,h,d] -> vt [b,h,d,s] ----------------
__global__ __launch_bounds__(256) void vtrans(const short* __restrict__ qkv, short* __restrict__ vt) {
  __shared__ __align__(16) short tile[64][72];
  int s0 = blockIdx.x*64;
  int z = blockIdx.y; int b = z >> 4, h = z & 15;
  int t = threadIdx.x;
  int rr = t >> 3, cc = (t & 7) * 8;
#pragma unroll
  for (int i = 0; i < 2; i++) {
    short8 v = *(const short8*)(qkv + (size_t)(b*SS + s0 + rr + i*32)*(3*DIM) + 2*DIM + h*HD + cc);
    *(short8*)&tile[rr + i*32][cc] = v;
  }
  __syncthreads();
#pragma unroll
  for (int i = 0; i < 2; i++) {
    int d = rr + i*32;
    short8 v;
#pragma unroll
    for (int j = 0; j < 8; j++) v[j] = tile[cc + j][d];
    *(short8*)(vt + ((size_t)z*HD + d)*SS + s0 + cc) = v;
  }
}

// ---------------- GEMM: C[M,N] = A[M,K] * Bt[N,K]^T  (m97 structure) ----------------
// EPI: 0 = none, 1 = relu, 3 = add fp32 residual.  CT: short (bf16 out) or float (fp32 out).
template<int EPI, typename CT>
__global__ __launch_bounds__(256) void gemm_bt(const short* __restrict__ A, int lda,
                                               const short* __restrict__ Bt, int ldb,
                                               CT* C, int ldc,
                                               const float* Res, int ldr,
                                               int K) {
  __shared__ __align__(16) short ldsA[128*32];
  __shared__ __align__(16) short ldsB[128*32];
  int t = threadIdx.x, lane = t & 63, wid = t >> 6;
  int bm = blockIdx.x*128, bn = blockIdx.y*128;
  int wr = wid >> 1, wc = wid & 1;
  f32x4 z4 = {0.f, 0.f, 0.f, 0.f};
  f32x4 acc[4][4];
#pragma unroll
  for (int m = 0; m < 4; m++)
#pragma unroll
    for (int n = 0; n < 4; n++) acc[m][n] = z4;
  const short* pa = A + (size_t)(bm + (t >> 2))*lda + (t & 3)*8;
  const short* pb = Bt + (size_t)(bn + (t >> 2))*ldb + (t & 3)*8;
  for (int k0 = 0; k0 < K; k0 += 32) {
    gload16(pa,                    &ldsA[wid*512]);
    gload16(pa + (size_t)64*lda,   &ldsA[2048 + wid*512]);
    gload16(pb,                    &ldsB[wid*512]);
    gload16(pb + (size_t)64*ldb,   &ldsB[2048 + wid*512]);
    pa += 32; pb += 32;
    __syncthreads();
    short8 af[4], bfr[4];
#pragma unroll
    for (int m = 0; m < 4; m++)
      af[m] = *(const short8*)&ldsA[(wr*64 + m*16 + (lane & 15))*32 + (lane >> 4)*8];
#pragma unroll
    for (int n = 0; n < 4; n++)
      bfr[n] = *(const short8*)&ldsB[(wc*64 + n*16 + (lane & 15))*32 + (lane >> 4)*8];
#pragma unroll
    for (int m = 0; m < 4; m++)
#pragma unroll
      for (int n = 0; n < 4; n++)
        acc[m][n] = __builtin_amdgcn_mfma_f32_16x16x32_bf16(af[m], bfr[n], acc[m][n], 0, 0, 0);
    __syncthreads();
  }
#pragma unroll
  for (int m = 0; m < 4; m++) {
    int r0 = bm + wr*64 + m*16 + ((lane >> 4) << 2);
#pragma unroll
    for (int n = 0; n < 4; n++) {
      int c = bn + wc*64 + n*16 + (lane & 15);
#pragma unroll
      for (int r = 0; r < 4; r++) {
        float v = acc[m][n][r];
        if constexpr (EPI == 1) v = fmaxf(v, 0.0f);
        if constexpr (EPI == 3) v += Res[(size_t)(r0 + r)*ldr + c];
        if constexpr (std::is_same<CT, float>::value)
          C[(size_t)(r0 + r)*ldc + c] = v;
        else
          C[(size_t)(r0 + r)*ldc + c] = f2b(v);
      }
    }
  }
}

// ---------------- causal flash attention (MFMA, LDS XOR-swizzled) ----------------
// grid: (S/64, B*NH); block 256 = 4 waves; wave w owns q-rows q0+w*16..+15.
// LDS swizzle (T2, rule #21): K/V staged by global_load_lds (linear dest) with
// per-lane PRE-SWIZZLED global source col; reads XOR the same involution.
// P written via ds_write with the same XOR on both sides.
// Block remap: pair (j, 31-j) -> constant 33 tiles per block pair (causal balance).
__global__ __launch_bounds__(256) void attn_k(short* qkv, const short* __restrict__ vt) {
  __shared__ __align__(16) short ldsK[64*64];
  __shared__ __align__(16) short ldsV[64*64];
  __shared__ __align__(16) short ldsP[4][16*64];
  int t = threadIdx.x, lane = t & 63, wid = t >> 6;
  int bx = blockIdx.x;
  int qi = (bx & 1) ? (31 - (bx >> 1)) : (bx >> 1);   // causal load balance
  int q0 = qi*64;
  int z = blockIdx.y; int b = z >> 4, h = z & 15;
  const int ld = 3*DIM;
  short8 qf[2];
  {
    const short* qp = qkv + (size_t)(b*SS + q0 + wid*16 + (lane & 15))*ld + h*HD + (lane >> 4)*8;
    qf[0] = *(const short8*)qp;
    qf[1] = *(const short8*)(qp + 32);
  }
  f32x4 z4 = {0.f, 0.f, 0.f, 0.f};
  f32x4 accO[4];
#pragma unroll
  for (int n = 0; n < 4; n++) accO[n] = z4;
  float m_r[4], l_r[4];
#pragma unroll
  for (int r = 0; r < 4; r++) { m_r[r] = -1e30f; l_r[r] = 0.f; }
  // staging source col, pre-swizzled: ((l&7)^(l>>3))*8 shorts (row&7 == l>>3)
  const int srcCol = (((lane & 7) ^ (lane >> 3)) * 8);
  const int rowXor = (lane & 7) << 3;   // read-side col XOR for row = *16 + (lane&15)
  int ntiles = qi + 1;   // causal: kv tiles 0 .. q-tile
  for (int it = 0; it < ntiles; ++it) {
    int kv0 = it*64;
    {
      const short* sk = qkv + (size_t)(b*SS + kv0 + (t >> 3))*ld + DIM + h*HD + srcCol;
      gload16(sk,                  &ldsK[wid*512]);
      gload16(sk + (size_t)32*ld,  &ldsK[2048 + wid*512]);
      const short* sv = vt + ((size_t)z*HD + (t >> 3))*SS + kv0 + srcCol;
      gload16(sv,                  &ldsV[wid*512]);
      gload16(sv + (size_t)32*SS,  &ldsV[2048 + wid*512]);
    }
    __syncthreads();
    f32x4 sacc[4];
#pragma unroll
    for (int n = 0; n < 4; n++) sacc[n] = z4;
#pragma unroll
    for (int n = 0; n < 4; n++) {
#pragma unroll
      for (int kk = 0; kk < 2; kk++) {
        int colK = (kk*32 + (lane >> 4)*8) ^ rowXor;
        short8 kb = *(const short8*)&ldsK[(n*16 + (lane & 15))*64 + colK];
        sacc[n] = __builtin_amdgcn_mfma_f32_16x16x32_bf16(qf[kk], kb, sacc[n], 0, 0, 0);
      }
    }
    float al[4];
#pragma unroll
    for (int r = 0; r < 4; r++) {
      int qg = q0 + wid*16 + ((lane >> 4) << 2) + r;
      float mx = -1e30f;
#pragma unroll
      for (int n = 0; n < 4; n++) {
        int kg = kv0 + n*16 + (lane & 15);
        float s = sacc[n][r] * 0.125f;       // 1/sqrt(HD) = 1/8 (verified r8)
        s = (kg <= qg) ? s : -1e30f;         // causal mask
        sacc[n][r] = s;
        mx = fmaxf(mx, s);
      }
#pragma unroll
      for (int off = 1; off < 16; off <<= 1) mx = fmaxf(mx, __shfl_xor(mx, off));
      float mn = fmaxf(m_r[r], mx);
      al[r] = __expf(m_r[r] - mn);
      float rsum = 0.f;
#pragma unroll
      for (int n = 0; n < 4; n++) {
        float p = __expf(sacc[n][r] - mn);
        sacc[n][r] = p;
        rsum += p;
      }
#pragma unroll
      for (int off = 1; off < 16; off <<= 1) rsum += __shfl_xor(rsum, off);
      l_r[r] = l_r[r]*al[r] + rsum;
      m_r[r] = mn;
    }
#pragma unroll
    for (int n = 0; n < 4; n++)
#pragma unroll
      for (int r = 0; r < 4; r++) accO[n][r] *= al[r];
    // P (D-layout) -> per-wave LDS in A-operand layout (XOR-swizzled both sides)
#pragma unroll
    for (int n = 0; n < 4; n++)
#pragma unroll
      for (int r = 0; r < 4; r++) {
        int prow = ((lane >> 4) << 2) + r;
        int pcol = (n*16 + (lane & 15)) ^ ((prow & 7) << 3);
        ldsP[wid][prow*64 + pcol] = f2b(sacc[n][r]);
      }
    __syncthreads();
#pragma unroll
    for (int nn = 0; nn < 4; nn++) {
#pragma unroll
      for (int kk = 0; kk < 2; kk++) {
        int colP = (kk*32 + (lane >> 4)*8) ^ rowXor;   // row = lane&15, row&7 = lane&7
        short8 pfr = *(const short8*)&ldsP[wid][(lane & 15)*64 + colP];
        short8 vb  = *(const short8*)&ldsV[(nn*16 + (lane & 15))*64 + colP];
        accO[nn] = __builtin_amdgcn_mfma_f32_16x16x32_bf16(pfr, vb, accO[nn], 0, 0, 0);
      }
    }
    __syncthreads();
  }
#pragma unroll
  for (int nn = 0; nn < 4; nn++) {
#pragma unroll
    for (int r = 0; r < 4; r++) {
      int qg = q0 + wid*16 + ((lane >> 4) << 2) + r;
      float ov = accO[nn][r] / l_r[r];
      qkv[(size_t)(b*SS + qg)*ld + 2*DIM + h*HD + nn*16 + (lane & 15)] = f2b(ov);
    }
  }
}

extern "C" void kernel_launch(void* const* d_in, const int* in_sizes, int n_in,
                              void* d_out, int out_size, void* d_ws, size_t ws_size,
                              hipStream_t stream) {
  (void)in_sizes; (void)n_in; (void)out_size; (void)ws_size;
  const float* x    = (const float*)d_in[0];
  // d_in[1] = mask: causal with -1e9 fill -> applied analytically, ignored
  const float* wq   = (const float*)d_in[2];
  const float* wk   = (const float*)d_in[3];
  const float* wv   = (const float*)d_in[4];
  const float* wo   = (const float*)d_in[5];
  const float* w1   = (const float*)d_in[6];
  const float* w2   = (const float*)d_in[7];
  const float* ln1w = (const float*)d_in[8];
  const float* ln1b = (const float*)d_in[9];
  const float* ln2w = (const float*)d_in[10];
  const float* ln2b = (const float*)d_in[11];
  float* out = (float*)d_out;   // fp32 output (verified r8)

  short* ws = (short*)d_ws;
  size_t o = 0;
  short* wqkvT = ws + o; o += (size_t)3*DIM*DIM;   // [3072][1024] bf16
  short* woT   = ws + o; o += (size_t)DIM*DIM;     // [1024][1024]
  short* w1T   = ws + o; o += (size_t)HID*DIM;     // [4096][1024]
  short* w2T   = ws + o; o += (size_t)DIM*HID;     // [1024][4096]
  short* xn    = ws + o; o += (size_t)NROW*DIM;    // LN1 out -> LN2 out (disjoint lifetimes)
  short* qkv   = ws + o; o += (size_t)NROW*3*DIM;  // q|k|v cols; v cols overwritten by attn out
  short* ff1   = ws + o; o += (size_t)NROW*HID;    // relu(hn@w1); front 16MB doubles as vt earlier
  short* vtb   = ff1;                              // [b,h,d,s] — lifetime disjoint from ff1

  dim3 B256(256);
  // weight transposes (fp32 -> bf16, B^T convention for gemm_bt)
  transp_f2b<<<dim3(16,16), B256, 0, stream>>>(wq, wqkvT,             DIM, DIM);
  transp_f2b<<<dim3(16,16), B256, 0, stream>>>(wk, wqkvT + DIM*DIM,   DIM, DIM);
  transp_f2b<<<dim3(16,16), B256, 0, stream>>>(wv, wqkvT + 2*DIM*DIM, DIM, DIM);
  transp_f2b<<<dim3(16,16), B256, 0, stream>>>(wo, woT, DIM, DIM);
  transp_f2b<<<dim3(16,64), B256, 0, stream>>>(w1, w1T, DIM, HID);
  transp_f2b<<<dim3(64,16), B256, 0, stream>>>(w2, w2T, HID, DIM);
  // xn = LN1(x)   (fp32 in, bf16 out)
  ln_k<<<NROW, B256, 0, stream>>>(x, ln1w, ln1b, xn);
  // qkv = xn @ [wq|wk|wv]   (bf16 out)
  gemm_bt<0, short><<<dim3(NROW/128, 3*DIM/128), B256, 0, stream>>>(xn, DIM, wqkvT, DIM, qkv, 3*DIM, nullptr, 0, DIM);
  // vt = transpose(v) per (b,h)
  vtrans<<<dim3(SS/64, BB*NH), B256, 0, stream>>>(qkv, vtb);
  // attention (writes into qkv v-columns, bf16)
  attn_k<<<dim3(SS/64, BB*NH), B256, 0, stream>>>(qkv, vtb);
  // h = x + attn @ wo   (fp32 h in d_out)
  gemm_bt<3, float><<<dim3(NROW/128, DIM/128), B256, 0, stream>>>(qkv + 2*DIM, 3*DIM, woT, DIM, out, DIM, x, DIM, DIM);
  // hn = LN2(h) (fp32 in, bf16 out into xn)
  ln_k<<<NROW, B256, 0, stream>>>(out, ln2w, ln2b, xn);
  // ff1 = relu(hn @ w1)  (bf16 out)
  gemm_bt<1, short><<<dim3(NROW/128, HID/128), B256, 0, stream>>>(xn, DIM, w1T, DIM, ff1, HID, nullptr, 0, DIM);
  // out = h + ff1 @ w2   (fp32 in-place residual: each element read+written by its own thread)
  gemm_bt<3, float><<<dim3(NROW/128, DIM/128), B256, 0, stream>>>(ff1, HID, w2T, HID, out, DIM, out, DIM, HID);
}